// Round 9
// baseline (1416.480 us; speedup 1.0000x reference)
//
#include <hip/hip_runtime.h>
#include <hip/hip_cooperative_groups.h>

namespace cg = cooperative_groups;

#define NN 50000
#define EE 800000

#define BKT 196       // buckets = dst>>8 (256 nodes each)
#define CGB 256       // cooperative blocks
#define EPB2 3125     // edges per coop block (256*3125 = 800000 = E exactly)
#define CAP 5120      // LDS staging capacity per bucket (mean 4081)

typedef unsigned short u16;
typedef unsigned int u32;
typedef __attribute__((ext_vector_type(8))) short short8;   // 8 bf16 (4 VGPRs)
typedef __attribute__((ext_vector_type(4))) float f32x4;
typedef __attribute__((ext_vector_type(4))) unsigned short ushort4v;

__device__ __forceinline__ float b2f(u16 u) {
    return __uint_as_float(((unsigned)u) << 16);
}
__device__ __forceinline__ u16 f2b(float f) {
    unsigned u = __float_as_uint(f);
    return (u16)((u + 0x7FFF + ((u >> 16) & 1)) >> 16);   // RNE
}

// ---------------------------------------------------------------------------
// ONE cooperative dispatch: CSR build (hist -> 2-level scan -> scatter ->
// bucket sort) + weight fragment packing on otherwise-idle blocks.
// csr entry = (dstLow << 16) | src   (src < 2^16, dstLow = dst & 255)
// ---------------------------------------------------------------------------
__global__ __launch_bounds__(256) void csr_coop(
    const int* __restrict__ src, const int* __restrict__ dst,
    const float* __restrict__ W0, const float* __restrict__ W1,
    const float* __restrict__ W2, u16* __restrict__ Wf,
    int* __restrict__ BBC, int* __restrict__ bktTot, int* __restrict__ bktBase,
    int* __restrict__ S, u32* __restrict__ pairs,
    int* __restrict__ off, int* __restrict__ csr, int N, int E)
{
    cg::grid_group grid = cg::this_grid();
    __shared__ int sh[768 + CAP];
    const int g = blockIdx.x, t = threadIdx.x;
    const int beg = g * EPB2, end = min(E, beg + EPB2);

    // ---- A: per-block histogram over 196 buckets
    for (int b = t; b < BKT; b += 256) sh[b] = 0;
    __syncthreads();
    for (int e = beg + t; e < end; e += 256) atomicAdd(&sh[dst[e] >> 8], 1);
    __syncthreads();
    for (int b = t; b < BKT; b += 256) BBC[b * CGB + g] = sh[b];
    grid.sync();

    // ---- B1: bucket totals (blocks <196); prep_w on blocks 200..223
    if (g < BKT) {
        sh[t] = BBC[g * CGB + t];
        __syncthreads();
        for (int d = 128; d > 0; d >>= 1) {
            if (t < d) sh[t] += sh[t + d];
            __syncthreads();
        }
        if (t == 0) bktTot[g] = sh[0];
    } else if (g >= 200 && g < 224) {
        int u = (g - 200) * 4 + (t >> 6);       // 0..95
        int set = u >> 5, nt2 = (u >> 2) & 7, kt = u & 3;
        int lane = t & 63;
        const float* W = (set == 0) ? W0 : (set == 1) ? W1 : W2;
        int ld = (set == 2) ? 40 : 128;
        int ncols = (set == 2) ? 40 : 128;
        int n = nt2 * 16 + (lane & 15);
        int kb = kt * 32 + (lane >> 4) * 8;
        u16* dw = Wf + set * 16384 + (size_t)((nt2 * 4 + kt) * 64 + lane) * 8;
#pragma unroll
        for (int j = 0; j < 8; j++) {
            float v = (n < ncols) ? W[(kb + j) * ld + n] : 0.f;
            dw[j] = f2b(v);
        }
    }
    grid.sync();

    // ---- B2: exclusive scan of 196 bucket totals (block 0)
    if (g == 0) {
        int v = (t < BKT) ? bktTot[t] : 0;
        sh[t] = v;
        __syncthreads();
        for (int d = 1; d < 256; d <<= 1) {
            int u = (t >= d) ? sh[t - d] : 0;
            __syncthreads();
            sh[t] += u;
            __syncthreads();
        }
        if (t < BKT) bktBase[t] = sh[t] - v;
    }
    grid.sync();

    // ---- B3: within-bucket exclusive scan over 256 block-counts
    if (g < BKT) {
        int v = BBC[g * CGB + t];
        sh[t] = v;
        __syncthreads();
        for (int d = 1; d < 256; d <<= 1) {
            int u = (t >= d) ? sh[t - d] : 0;
            __syncthreads();
            sh[t] += u;
            __syncthreads();
        }
        S[g * CGB + t] = sh[t] - v + bktBase[g];
    }
    grid.sync();

    // ---- C: scatter packed (src<<8 | dstLow) into per-(bucket,block) segs
    for (int b = t; b < BKT; b += 256) sh[b] = S[b * CGB + g];
    __syncthreads();
    for (int e = beg + t; e < end; e += 256) {
        int d = dst[e];
        int pos = atomicAdd(&sh[d >> 8], 1);
        pairs[pos] = ((u32)src[e] << 8) | (u32)(d & 255);
    }
    grid.sync();

    // ---- D: per-bucket node sort, LDS-staged; csr = (dstLow<<16)|src
    if (g < BKT) {
        int* sdeg = sh;
        int* sex  = sh + 256;
        int* scur = sh + 512;
        int* stage = sh + 768;
        const int base = S[g * CGB];
        const int eE = (g == BKT - 1) ? E : S[(g + 1) * CGB];
        const int cnt = eE - base;
        sdeg[t] = 0;
        __syncthreads();
        for (int i = t; i < cnt; i += 256)
            atomicAdd(&sdeg[pairs[base + i] & 255], 1);
        __syncthreads();
        int v = sdeg[t];
        sex[t] = v;
        __syncthreads();
        for (int d = 1; d < 256; d <<= 1) {
            int u = (t >= d) ? sex[t - d] : 0;
            __syncthreads();
            sex[t] += u;
            __syncthreads();
        }
        const int excl = sex[t] - v;
        const int node = g * 256 + t;
        if (node < N) off[node] = base + excl;
        if (g == BKT - 1 && t == 0) off[N] = E;
        scur[t] = excl;
        __syncthreads();
        if (cnt <= CAP) {
            for (int i = t; i < cnt; i += 256) {
                u32 p = pairs[base + i];
                int pos = atomicAdd(&scur[p & 255], 1);
                stage[pos] = (int)(p >> 8) | ((int)(p & 255) << 16);
            }
            __syncthreads();
            for (int i = t; i < cnt; i += 256) csr[base + i] = stage[i];
        } else {
            for (int i = t; i < cnt; i += 256) {
                u32 p = pairs[base + i];
                int pos = atomicAdd(&scur[p & 255], 1);
                csr[base + pos] = (int)(p >> 8) | ((int)(p & 255) << 16);
            }
        }
    }
}

// ---------------------------------------------------------------------------
// layer-0 GEMM: t[n][m] = sum_k bf16(x[n][k]) * W0[k][m]   (fp32 input)
// ---------------------------------------------------------------------------
__global__ __launch_bounds__(256) void gemm0(
    const float* __restrict__ A, const u16* __restrict__ Wf,
    u16* __restrict__ out, int N)
{
    const int wave = threadIdx.x >> 6;
    const int lane = threadIdx.x & 63;
    const int m = lane & 15;
    const int q = lane >> 4;
    const int rowBase = blockIdx.x * 64 + wave * 16;
    const int arow = rowBase + m;
    const bool rowOk = (arow < N);

    short8 af[4];
#pragma unroll
    for (int kt = 0; kt < 4; kt++) {
        if (rowOk) {
            float4 lo = *(const float4*)(A + (size_t)arow * 128 + kt * 32 + q * 8);
            float4 hi = *(const float4*)(A + (size_t)arow * 128 + kt * 32 + q * 8 + 4);
            short8 v;
            v[0] = (short)f2b(lo.x); v[1] = (short)f2b(lo.y);
            v[2] = (short)f2b(lo.z); v[3] = (short)f2b(lo.w);
            v[4] = (short)f2b(hi.x); v[5] = (short)f2b(hi.y);
            v[6] = (short)f2b(hi.z); v[7] = (short)f2b(hi.w);
            af[kt] = v;
        } else {
            af[kt] = (short8)0;
        }
    }

    f32x4 acc[8];
#pragma unroll
    for (int nt = 0; nt < 8; nt++) acc[nt] = (f32x4)0.f;

#pragma unroll
    for (int kt = 0; kt < 4; kt++) {
#pragma unroll
        for (int nt = 0; nt < 8; nt++) {
            short8 bf = *(const short8*)(Wf + (size_t)((nt * 4 + kt) * 64 + lane) * 8);
            acc[nt] = __builtin_amdgcn_mfma_f32_16x16x32_bf16(af[kt], bf, acc[nt], 0, 0, 0);
        }
    }

#pragma unroll
    for (int nt = 0; nt < 8; nt++) {
#pragma unroll
        for (int r = 0; r < 4; r++) {
            int orow = rowBase + q * 4 + r;
            if (orow < N) out[(size_t)orow * 128 + nt * 16 + m] = f2b(acc[nt][r]);
        }
    }
}

// ---------------------------------------------------------------------------
// GEMM from bf16 rows (stride 128): out = A @ W, NT n-tiles, OSTRIDE out cols
// ---------------------------------------------------------------------------
template<int NT, int OSTRIDE>
__global__ __launch_bounds__(256) void gemm_b(
    const u16* __restrict__ A, const u16* __restrict__ Wf,
    u16* __restrict__ out, int N)
{
    const int wave = threadIdx.x >> 6;
    const int lane = threadIdx.x & 63;
    const int m = lane & 15;
    const int q = lane >> 4;
    const int rowBase = blockIdx.x * 64 + wave * 16;
    const int arow = rowBase + m;
    const bool rowOk = (arow < N);

    short8 af[4];
#pragma unroll
    for (int kt = 0; kt < 4; kt++) {
        af[kt] = rowOk ? *(const short8*)(A + (size_t)arow * 128 + kt * 32 + q * 8)
                       : (short8)0;
    }

    f32x4 acc[NT];
#pragma unroll
    for (int nt = 0; nt < NT; nt++) acc[nt] = (f32x4)0.f;

#pragma unroll
    for (int kt = 0; kt < 4; kt++) {
#pragma unroll
        for (int nt = 0; nt < NT; nt++) {
            short8 bf = *(const short8*)(Wf + (size_t)((nt * 4 + kt) * 64 + lane) * 8);
            acc[nt] = __builtin_amdgcn_mfma_f32_16x16x32_bf16(af[kt], bf, acc[nt], 0, 0, 0);
        }
    }

#pragma unroll
    for (int nt = 0; nt < NT; nt++) {
#pragma unroll
        for (int r = 0; r < 4; r++) {
            int orow = rowBase + q * 4 + r;
            if (orow < N) out[(size_t)orow * OSTRIDE + nt * 16 + m] = f2b(acc[nt][r]);
        }
    }
}

// ---------------------------------------------------------------------------
// edge-parallel chunked aggregation: grid (ceil(N/64), 4 chunks of 32 feats).
// Block owns 64 dst nodes; uniform loop over the block's contiguous CSR
// range (no per-node degree divergence); 4 lanes x 16B per edge; fp32 LDS
// accumulators (row stride 33 breaks the stride-32 16-way bank conflict).
// Epilogue: bias + relu -> bf16 out (stride 128).
// ---------------------------------------------------------------------------
__global__ __launch_bounds__(256) void agg_edge(
    const u16* __restrict__ val, const int* __restrict__ off,
    const int* __restrict__ csr, const float* __restrict__ bias,
    u16* __restrict__ out, int N)
{
    __shared__ float acc[64 * 33];
    const int t = threadIdx.x;
    const int base = blockIdx.x * 64;
    const int fb = blockIdx.y * 32;
    for (int i = t; i < 64 * 33; i += 256) acc[i] = 0.f;
    __syncthreads();

    const int eBeg = off[base];
    const int eEnd = off[min(base + 64, N)];
    const int sub = t & 3;
    const int foff = fb + sub * 8;

    int i = eBeg + (t >> 2);
    for (; i + 64 < eEnd; i += 128) {
        int e0 = csr[i];
        int e1 = csr[i + 64];
        short8 v0 = *(const short8*)(val + (size_t)(e0 & 0xFFFF) * 128 + foff);
        short8 v1 = *(const short8*)(val + (size_t)(e1 & 0xFFFF) * 128 + foff);
        float* a0 = &acc[((e0 >> 16) & 63) * 33 + sub * 8];
        float* a1 = &acc[((e1 >> 16) & 63) * 33 + sub * 8];
#pragma unroll
        for (int j = 0; j < 8; j++) atomicAdd(&a0[j], b2f((u16)v0[j]));
#pragma unroll
        for (int j = 0; j < 8; j++) atomicAdd(&a1[j], b2f((u16)v1[j]));
    }
    if (i < eEnd) {
        int e0 = csr[i];
        short8 v0 = *(const short8*)(val + (size_t)(e0 & 0xFFFF) * 128 + foff);
        float* a0 = &acc[((e0 >> 16) & 63) * 33 + sub * 8];
#pragma unroll
        for (int j = 0; j < 8; j++) atomicAdd(&a0[j], b2f((u16)v0[j]));
    }
    __syncthreads();

    const int row = t >> 2;
    const int node = base + row;
    if (node < N) {
        const float* a = &acc[row * 33 + sub * 8];
        const float* b = bias + foff;
        short8 o;
#pragma unroll
        for (int j = 0; j < 8; j++)
            o[j] = (short)f2b(fmaxf(a[j] + b[j], 0.f));
        *(short8*)(out + (size_t)node * 128 + foff) = o;
    }
}

// ---------------------------------------------------------------------------
// aggregate first 40 feats of bf16 stride-48 rows, + b2 -> fp32 d_out
// ---------------------------------------------------------------------------
__global__ __launch_bounds__(256) void agg40b(
    const u16* __restrict__ val, const int* __restrict__ off,
    const int* __restrict__ csr, const float* __restrict__ b2,
    float* __restrict__ out, int N)
{
    const int c = threadIdx.x & 15;
    const int node = blockIdx.x * 16 + (threadIdx.x >> 4);
    if (node >= N || c >= 10) return;
    const int beg = off[node], end = off[node + 1];

    float a0[4] = {0, 0, 0, 0};
    float a1[4] = {0, 0, 0, 0};
    int i = beg;
    for (; i + 1 < end; i += 2) {
        int s0 = csr[i] & 0xFFFF;
        int s1 = csr[i + 1] & 0xFFFF;
        ushort4v v0 = *(const ushort4v*)(val + (size_t)s0 * 48 + c * 4);
        ushort4v v1 = *(const ushort4v*)(val + (size_t)s1 * 48 + c * 4);
        a0[0] += b2f(v0.x); a0[1] += b2f(v0.y); a0[2] += b2f(v0.z); a0[3] += b2f(v0.w);
        a1[0] += b2f(v1.x); a1[1] += b2f(v1.y); a1[2] += b2f(v1.z); a1[3] += b2f(v1.w);
    }
    if (i < end) {
        int s0 = csr[i] & 0xFFFF;
        ushort4v v0 = *(const ushort4v*)(val + (size_t)s0 * 48 + c * 4);
        a0[0] += b2f(v0.x); a0[1] += b2f(v0.y); a0[2] += b2f(v0.z); a0[3] += b2f(v0.w);
    }
    float4 b = *(const float4*)(b2 + c * 4);
    float4 r;
    r.x = a0[0] + a1[0] + b.x;
    r.y = a0[1] + a1[1] + b.y;
    r.z = a0[2] + a1[2] + b.z;
    r.w = a0[3] + a1[3] + b.w;
    *(float4*)(out + (size_t)node * 40 + c * 4) = r;
}

extern "C" void kernel_launch(void* const* d_in, const int* in_sizes, int n_in,
                              void* d_out, int out_size, void* d_ws, size_t ws_size,
                              hipStream_t stream)
{
    const float* x  = (const float*)d_in[0];
    const int*   ei = (const int*)d_in[1];
    const float* W0 = (const float*)d_in[2];
    const float* b0 = (const float*)d_in[3];
    const float* W1 = (const float*)d_in[4];
    const float* b1 = (const float*)d_in[5];
    const float* W2 = (const float*)d_in[6];
    const float* b2 = (const float*)d_in[7];
    float* out = (float*)d_out;

    int N = NN, E = EE;
    const int* src = ei;        // edge_index[0]
    const int* dst = ei + E;    // edge_index[1]

    char* ws = (char*)d_ws;
    u16* t       = (u16*)ws;                        // 12.8 MB (GEMM out)
    u16* hb      = (u16*)(ws + 12800000);           // 12.8 MB (agg out)
    u16* t2      = (u16*)(ws + 25600000);           // 4.8 MB (layer-2 GEMM out)
    u16* Wf      = (u16*)(ws + 30400000);           // 96 KB (frag-packed W)
    int* off     = (int*)(ws + 30500000);           // 200 KB (N+1)
    int* csr     = (int*)(ws + 30700008);           // 3.2 MB (packed dst|src)
    int* BBC     = (int*)(ws + 33900008);           // 200.7 KB
    int* S       = (int*)(ws + 34100712);           // 200.7 KB
    int* bktTot  = (int*)(ws + 34301416);           // 784 B
    int* bktBase = (int*)(ws + 34302200);           // 784 B
    u32* pairs   = (u32*)(ws + 34302984);           // 3.2 MB (packed)

    const int tileGrid = (N + 63) / 64;             // 782
    const int agg40Grid = (N + 15) / 16;            // 3125

    // ---- 1 dispatch: CSR build + weight packing (cooperative)
    void* args[] = {
        (void*)&src, (void*)&dst, (void*)&W0, (void*)&W1, (void*)&W2,
        (void*)&Wf, (void*)&BBC, (void*)&bktTot, (void*)&bktBase,
        (void*)&S, (void*)&pairs, (void*)&off, (void*)&csr,
        (void*)&N, (void*)&E
    };
    hipLaunchCooperativeKernel((void*)csr_coop, dim3(CGB), dim3(256),
                               args, 0, stream);

    // ---- layer 0: t = bf16(x) @ W0
    gemm0<<<tileGrid, 256, 0, stream>>>(x, Wf, t, N);

    // ---- layer 1: hb = relu(agg(t) + b0) ; t = hb @ W1
    agg_edge<<<dim3(tileGrid, 4), 256, 0, stream>>>(t, off, csr, b0, hb, N);
    gemm_b<8, 128><<<tileGrid, 256, 0, stream>>>(hb, Wf + 16384, t, N);

    // ---- layer 2: hb = relu(agg(t) + b1) ; t2 = hb @ W2pad (48 cols)
    agg_edge<<<dim3(tileGrid, 4), 256, 0, stream>>>(t, off, csr, b1, hb, N);
    gemm_b<3, 48><<<tileGrid, 256, 0, stream>>>(hb, Wf + 32768, t2, N);

    // ---- final: out = agg40(t2) + b2
    agg40b<<<agg40Grid, 256, 0, stream>>>(t2, off, csr, b2, out, N);
}

// Round 10
// 209.708 us; speedup vs baseline: 6.7545x; 6.7545x over previous
//
#include <hip/hip_runtime.h>

#define NN 50000
#define EE 800000

#define BKT 196      // buckets = dst>>8 (256 nodes each)
#define GB  334      // histogram/scatter blocks
#define EPB 2396     // edges per block (334*2396 = 800264 >= E)
#define CAP 5120     // LDS staging capacity per bucket (mean 4081)

typedef unsigned short u16;
typedef unsigned int u32;
typedef __attribute__((ext_vector_type(8))) short short8;   // 8 bf16 (4 VGPRs)
typedef __attribute__((ext_vector_type(4))) float f32x4;
typedef __attribute__((ext_vector_type(4))) unsigned short ushort4v;

__device__ __forceinline__ float b2f(u16 u) {
    return __uint_as_float(((unsigned)u) << 16);
}
__device__ __forceinline__ u16 f2b(float f) {
    unsigned u = __float_as_uint(f);
    return (u16)((u + 0x7FFF + ((u >> 16) & 1)) >> 16);   // RNE
}

// ---------------------------------------------------------------------------
// K1: blocks [0,GB) = per-block LDS histogram over 196 buckets (dst>>8);
//     blocks [GB,GB+24) = pack W0/W1/W2(padded) into MFMA B-fragment order.
// ---------------------------------------------------------------------------
__global__ __launch_bounds__(256) void hist_prep(
    const int* __restrict__ dst, int* __restrict__ BBC,
    const float* __restrict__ W0, const float* __restrict__ W1,
    const float* __restrict__ W2, u16* __restrict__ Wf, int E)
{
    __shared__ int cnt[BKT];
    const int g = blockIdx.x, t = threadIdx.x;
    if (g < GB) {
        for (int b = t; b < BKT; b += 256) cnt[b] = 0;
        __syncthreads();
        const int beg = g * EPB, end = min(E, beg + EPB);
        for (int e = beg + t; e < end; e += 256)
            atomicAdd(&cnt[dst[e] >> 8], 1);
        __syncthreads();
        for (int b = t; b < BKT; b += 256) BBC[b * GB + g] = cnt[b];
    } else {
        int u = (g - GB) * 4 + (t >> 6);        // 0..95
        int set = u >> 5, nt2 = (u >> 2) & 7, kt = u & 3;
        int lane = t & 63;
        const float* W = (set == 0) ? W0 : (set == 1) ? W1 : W2;
        int ld = (set == 2) ? 40 : 128;
        int ncols = (set == 2) ? 40 : 128;
        int n = nt2 * 16 + (lane & 15);
        int kb = kt * 32 + (lane >> 4) * 8;
        u16* dw = Wf + set * 16384 + (size_t)((nt2 * 4 + kt) * 64 + lane) * 8;
#pragma unroll
        for (int j = 0; j < 8; j++) {
            float v = (n < ncols) ? W[(kb + j) * ld + n] : 0.f;
            dw[j] = f2b(v);
        }
    }
}

// ---------------------------------------------------------------------------
// K2: per-block exclusive scan of 1024 elems, block total -> blockSums
// ---------------------------------------------------------------------------
__global__ __launch_bounds__(1024) void block_scan(
    const int* __restrict__ in, int* __restrict__ out,
    int* __restrict__ blockSums, int M)
{
    __shared__ int sh[1024];
    const int t = threadIdx.x;
    const int idx = blockIdx.x * 1024 + t;
    const int v = (idx < M) ? in[idx] : 0;
    sh[t] = v;
    __syncthreads();
    for (int d = 1; d < 1024; d <<= 1) {
        int u = (t >= d) ? sh[t - d] : 0;
        __syncthreads();
        sh[t] += u;
        __syncthreads();
    }
    if (idx < M) out[idx] = sh[t] - v;
    if (t == 1023) blockSums[blockIdx.x] = sh[t];
}

// ---------------------------------------------------------------------------
// K3: add block base; each block redundantly scans the 64 partials in LDS
// (merges old scan_sums + add_base into one dispatch)
// ---------------------------------------------------------------------------
__global__ __launch_bounds__(1024) void add_base_scan(
    int* __restrict__ S, const int* __restrict__ blockSums, int M, int nb)
{
    __shared__ int sb[64];
    const int t = threadIdx.x;
    if (t < 64) sb[t] = (t < nb) ? blockSums[t] : 0;
    __syncthreads();
    if (t == 0) {
        int run = 0;
        for (int i = 0; i < 64; i++) { int v = sb[i]; sb[i] = run; run += v; }
    }
    __syncthreads();
    const int base = sb[blockIdx.x];
    const int idx = blockIdx.x * 1024 + t;
    if (idx < M) S[idx] += base;
}

// ---------------------------------------------------------------------------
// K4: blocks [0,GB) = scatter packed (src<<8 | dstLow) into per-(bucket,block)
//     segments; blocks [GB,GB+gemmGrid) = layer-0 GEMM t = bf16(x) @ W0.
//     Independent ops -> scatter's latency hides under the GEMM.
// ---------------------------------------------------------------------------
__global__ __launch_bounds__(256) void scatter_gemm0(
    const int* __restrict__ src, const int* __restrict__ dst,
    const int* __restrict__ S, u32* __restrict__ pairs,
    const float* __restrict__ A, const u16* __restrict__ Wf,
    u16* __restrict__ out, int N, int E)
{
    __shared__ int cur[BKT];
    const int t = threadIdx.x;
    if (blockIdx.x < GB) {
        const int g = blockIdx.x;
        for (int b = t; b < BKT; b += 256) cur[b] = S[b * GB + g];
        __syncthreads();
        const int beg = g * EPB, end = min(E, beg + EPB);
        for (int e = beg + t; e < end; e += 256) {
            int d = dst[e];
            int pos = atomicAdd(&cur[d >> 8], 1);
            pairs[pos] = ((u32)src[e] << 8) | (u32)(d & 255);
        }
        return;
    }
    // ---- gemm0 ----
    const int bx = blockIdx.x - GB;
    const int wave = t >> 6;
    const int lane = t & 63;
    const int m = lane & 15;
    const int q = lane >> 4;
    const int rowBase = bx * 64 + wave * 16;
    const int arow = rowBase + m;
    const bool rowOk = (arow < N);

    short8 af[4];
#pragma unroll
    for (int kt = 0; kt < 4; kt++) {
        if (rowOk) {
            float4 lo = *(const float4*)(A + (size_t)arow * 128 + kt * 32 + q * 8);
            float4 hi = *(const float4*)(A + (size_t)arow * 128 + kt * 32 + q * 8 + 4);
            short8 v;
            v[0] = (short)f2b(lo.x); v[1] = (short)f2b(lo.y);
            v[2] = (short)f2b(lo.z); v[3] = (short)f2b(lo.w);
            v[4] = (short)f2b(hi.x); v[5] = (short)f2b(hi.y);
            v[6] = (short)f2b(hi.z); v[7] = (short)f2b(hi.w);
            af[kt] = v;
        } else {
            af[kt] = (short8)0;
        }
    }

    f32x4 acc[8];
#pragma unroll
    for (int nt = 0; nt < 8; nt++) acc[nt] = (f32x4)0.f;

#pragma unroll
    for (int kt = 0; kt < 4; kt++) {
#pragma unroll
        for (int nt = 0; nt < 8; nt++) {
            short8 bf = *(const short8*)(Wf + (size_t)((nt * 4 + kt) * 64 + lane) * 8);
            acc[nt] = __builtin_amdgcn_mfma_f32_16x16x32_bf16(af[kt], bf, acc[nt], 0, 0, 0);
        }
    }

#pragma unroll
    for (int nt = 0; nt < 8; nt++) {
#pragma unroll
        for (int r = 0; r < 4; r++) {
            int orow = rowBase + q * 4 + r;
            if (orow < N) out[(size_t)orow * 128 + nt * 16 + m] = f2b(acc[nt][r]);
        }
    }
}

// ---------------------------------------------------------------------------
// K5: per-bucket node sort, fully LDS-staged; csr entries = plain src
// ---------------------------------------------------------------------------
__global__ __launch_bounds__(256) void bucket_sort(
    const u32* __restrict__ pairs, const int* __restrict__ S,
    int* __restrict__ off, int* __restrict__ csr, int N, int E)
{
    __shared__ int sdeg[256];
    __shared__ int sex[256];
    __shared__ int scur[256];
    __shared__ int stage[CAP];
    const int b = blockIdx.x, t = threadIdx.x;
    const int base = S[b * GB];
    const int end  = (b == BKT - 1) ? E : S[(b + 1) * GB];
    const int cnt = end - base;

    sdeg[t] = 0;
    __syncthreads();
    for (int i = t; i < cnt; i += 256)
        atomicAdd(&sdeg[pairs[base + i] & 255], 1);
    __syncthreads();

    int v = sdeg[t];
    sex[t] = v;
    __syncthreads();
    for (int d = 1; d < 256; d <<= 1) {
        int u = (t >= d) ? sex[t - d] : 0;
        __syncthreads();
        sex[t] += u;
        __syncthreads();
    }
    const int excl = sex[t] - v;
    const int node = b * 256 + t;
    if (node < N) off[node] = base + excl;
    if (b == BKT - 1 && t == 0) off[N] = E;
    scur[t] = excl;
    __syncthreads();

    if (cnt <= CAP) {
        for (int i = t; i < cnt; i += 256) {
            u32 p = pairs[base + i];
            int pos = atomicAdd(&scur[p & 255], 1);
            stage[pos] = (int)(p >> 8);
        }
        __syncthreads();
        for (int i = t; i < cnt; i += 256) csr[base + i] = stage[i];
    } else {
        for (int i = t; i < cnt; i += 256) {
            u32 p = pairs[base + i];
            int pos = atomicAdd(&scur[p & 255], 1);
            csr[base + pos] = (int)(p >> 8);
        }
    }
}

// ---------------------------------------------------------------------------
// K6/K7: FUSED layer: out = ( relu(agg(val) + bias) ) @ W
// block = 64 dst nodes, 512 threads (8 waves).
// phase 1: gather-aggregate 64 rows -> LDS (bf16, row stride 136)
// phase 2: MFMA from LDS; wave = (rowGroup 0..3) x (colHalf 0..1)
// NOTE: reads `val`, writes `out` -- MUST be different buffers (cross-block
// gather makes in-place a race).
// ---------------------------------------------------------------------------
template<int NT, int OSTRIDE>
__global__ __launch_bounds__(512) void agg_gemm_t(
    const u16* __restrict__ val, const int* __restrict__ off,
    const int* __restrict__ csr, const float* __restrict__ bias,
    const u16* __restrict__ Wf, u16* __restrict__ out, int N)
{
    __shared__ u16 A[64][136];   // 17.4 KB
    const int tid = threadIdx.x;
    const int rowBase = blockIdx.x * 64;

    // ---- phase 1: aggregate, bias+relu, bf16 -> LDS
    {
        const int c = tid & 15;          // 16B chunk (8 bf16)
        const int nl = tid >> 4;         // 0..31
        float4 bA = *(const float4*)(bias + c * 8);
        float4 bB = *(const float4*)(bias + c * 8 + 4);
        float bb[8] = {bA.x, bA.y, bA.z, bA.w, bB.x, bB.y, bB.z, bB.w};
#pragma unroll
        for (int g = 0; g < 2; g++) {
            const int lrow = g * 32 + nl;
            const int node = rowBase + lrow;
            float a0[8] = {0, 0, 0, 0, 0, 0, 0, 0};
            float a1[8] = {0, 0, 0, 0, 0, 0, 0, 0};
            if (node < N) {
                const int beg = off[node], end = off[node + 1];
                int i = beg;
                for (; i + 3 < end; i += 4) {
                    int s0 = csr[i];
                    int s1 = csr[i + 1];
                    int s2 = csr[i + 2];
                    int s3 = csr[i + 3];
                    short8 v0 = *(const short8*)(val + (size_t)s0 * 128 + c * 8);
                    short8 v1 = *(const short8*)(val + (size_t)s1 * 128 + c * 8);
                    short8 v2 = *(const short8*)(val + (size_t)s2 * 128 + c * 8);
                    short8 v3 = *(const short8*)(val + (size_t)s3 * 128 + c * 8);
#pragma unroll
                    for (int j = 0; j < 8; j++) {
                        a0[j] += b2f((u16)v0[j]) + b2f((u16)v2[j]);
                        a1[j] += b2f((u16)v1[j]) + b2f((u16)v3[j]);
                    }
                }
                for (; i < end; i++) {
                    int s0 = csr[i];
                    short8 v0 = *(const short8*)(val + (size_t)s0 * 128 + c * 8);
#pragma unroll
                    for (int j = 0; j < 8; j++) a0[j] += b2f((u16)v0[j]);
                }
            }
            short8 o;
#pragma unroll
            for (int j = 0; j < 8; j++)
                o[j] = (short)f2b(fmaxf(a0[j] + a1[j] + bb[j], 0.f));
            *(short8*)&A[lrow][c * 8] = o;
        }
    }
    __syncthreads();

    // ---- phase 2: MFMA from LDS
    const int wave = tid >> 6;           // 0..7
    const int lane = tid & 63;
    const int m = lane & 15;
    const int q = lane >> 4;
    const int rg = wave & 3;             // row group (16 rows)
    const int ch = wave >> 2;            // col half
    const int lrow = rg * 16 + m;

    short8 af[4];
#pragma unroll
    for (int kt = 0; kt < 4; kt++)
        af[kt] = *(const short8*)&A[lrow][kt * 32 + q * 8];

    constexpr int NTH = (NT + 1) / 2;
    const int ntB = ch ? NTH : 0;
    const int ntE = ch ? NT : NTH;

    f32x4 acc[NTH];
#pragma unroll
    for (int i = 0; i < NTH; i++) acc[i] = (f32x4)0.f;

#pragma unroll
    for (int kt = 0; kt < 4; kt++) {
        for (int nt = ntB; nt < ntE; nt++) {
            short8 bf = *(const short8*)(Wf + (size_t)((nt * 4 + kt) * 64 + lane) * 8);
            acc[nt - ntB] = __builtin_amdgcn_mfma_f32_16x16x32_bf16(af[kt], bf, acc[nt - ntB], 0, 0, 0);
        }
    }

    for (int nt = ntB; nt < ntE; nt++) {
#pragma unroll
        for (int r = 0; r < 4; r++) {
            int orow = rowBase + rg * 16 + q * 4 + r;
            if (orow < N) out[(size_t)orow * OSTRIDE + nt * 16 + m] = f2b(acc[nt - ntB][r]);
        }
    }
}

// ---------------------------------------------------------------------------
// K8: aggregate first 40 feats of bf16 stride-48 rows, + b2 -> fp32 d_out
// ---------------------------------------------------------------------------
__global__ __launch_bounds__(256) void agg40b(
    const u16* __restrict__ val, const int* __restrict__ off,
    const int* __restrict__ csr, const float* __restrict__ b2,
    float* __restrict__ out, int N)
{
    const int c = threadIdx.x & 15;
    const int node = blockIdx.x * 16 + (threadIdx.x >> 4);
    if (node >= N || c >= 10) return;
    const int beg = off[node], end = off[node + 1];

    float a0[4] = {0, 0, 0, 0};
    float a1[4] = {0, 0, 0, 0};
    int i = beg;
    for (; i + 1 < end; i += 2) {
        int s0 = csr[i];
        int s1 = csr[i + 1];
        ushort4v v0 = *(const ushort4v*)(val + (size_t)s0 * 48 + c * 4);
        ushort4v v1 = *(const ushort4v*)(val + (size_t)s1 * 48 + c * 4);
        a0[0] += b2f(v0.x); a0[1] += b2f(v0.y); a0[2] += b2f(v0.z); a0[3] += b2f(v0.w);
        a1[0] += b2f(v1.x); a1[1] += b2f(v1.y); a1[2] += b2f(v1.z); a1[3] += b2f(v1.w);
    }
    if (i < end) {
        int s0 = csr[i];
        ushort4v v0 = *(const ushort4v*)(val + (size_t)s0 * 48 + c * 4);
        a0[0] += b2f(v0.x); a0[1] += b2f(v0.y); a0[2] += b2f(v0.z); a0[3] += b2f(v0.w);
    }
    float4 b = *(const float4*)(b2 + c * 4);
    float4 r;
    r.x = a0[0] + a1[0] + b.x;
    r.y = a0[1] + a1[1] + b.y;
    r.z = a0[2] + a1[2] + b.z;
    r.w = a0[3] + a1[3] + b.w;
    *(float4*)(out + (size_t)node * 40 + c * 4) = r;
}

extern "C" void kernel_launch(void* const* d_in, const int* in_sizes, int n_in,
                              void* d_out, int out_size, void* d_ws, size_t ws_size,
                              hipStream_t stream)
{
    const float* x  = (const float*)d_in[0];
    const int*   ei = (const int*)d_in[1];
    const float* W0 = (const float*)d_in[2];
    const float* b0 = (const float*)d_in[3];
    const float* W1 = (const float*)d_in[4];
    const float* b1 = (const float*)d_in[5];
    const float* W2 = (const float*)d_in[6];
    const float* b2 = (const float*)d_in[7];
    float* out = (float*)d_out;

    const int N = NN, E = EE;
    const int* src = ei;        // edge_index[0]
    const int* dst = ei + E;    // edge_index[1]

    char* ws = (char*)d_ws;
    u16* t       = (u16*)ws;                        // 12.8 MB (layer-0 GEMM out)
    u16* tB      = (u16*)(ws + 12800000);           // 12.8 MB (layer-1 fused out)
    u16* t2      = (u16*)(ws + 25600000);           // 4.8 MB (layer-2 fused out)
    u16* Wf      = (u16*)(ws + 30400000);           // 96 KB (frag-packed W)
    int* off     = (int*)(ws + 30500000);           // 200 KB (N+1)
    int* csr     = (int*)(ws + 30700008);           // 3.2 MB
    int* BBC     = (int*)(ws + 33900008);           // 262 KB
    int* S       = (int*)(ws + 34161864);           // 262 KB
    int* blkSums = (int*)(ws + 34423720);           // 256 B
    u32* pairs   = (u32*)(ws + 34423976);           // 3.2 MB

    const int M = BKT * GB;                         // 65464
    const int nScan = (M + 1023) / 1024;            // 64
    const int tileGrid = (N + 63) / 64;             // 782
    const int agg40Grid = (N + 15) / 16;            // 3125

    // K1: histogram + weight packing
    hist_prep<<<GB + 24, 256, 0, stream>>>(dst, BBC, W0, W1, W2, Wf, E);
    // K2/K3: two-level exclusive scan of (bucket,block) counts
    block_scan<<<nScan, 1024, 0, stream>>>(BBC, S, blkSums, M);
    add_base_scan<<<nScan, 1024, 0, stream>>>(S, blkSums, M, nScan);
    // K4: scatter pairs + layer-0 GEMM (independent, one launch)
    scatter_gemm0<<<GB + tileGrid, 256, 0, stream>>>(src, dst, S, pairs,
                                                     x, Wf, t, N, E);
    // K5: per-bucket sort -> off[] + csr[]
    bucket_sort<<<BKT, 256, 0, stream>>>(pairs, S, off, csr, N, E);

    // K6: layer 1 fused: tB = relu(agg(t) + b0) @ W1
    agg_gemm_t<8, 128><<<tileGrid, 512, 0, stream>>>(t, off, csr, b0,
                                                     Wf + 16384, tB, N);
    // K7: layer 2 fused: t2 = relu(agg(tB) + b1) @ W2pad (48 cols)
    agg_gemm_t<3, 48><<<tileGrid, 512, 0, stream>>>(tB, off, csr, b1,
                                                    Wf + 32768, t2, N);
    // K8: out = agg40(t2) + b2
    agg40b<<<agg40Grid, 256, 0, stream>>>(t2, off, csr, b2, out, N);
}

// Round 12
// 207.584 us; speedup vs baseline: 6.8236x; 1.0102x over previous
//
#include <hip/hip_runtime.h>

#define NN 50000
#define EE 800000

#define BKT 196      // buckets = dst>>8 (256 nodes each)
#define GB  334      // scatter blocks
#define EPB 2396     // edges per block (334*2396 = 800264 >= E)
#define CAPB 6144    // fixed bucket capacity (mean 4096, +32 sigma)
#define CAP 5120     // LDS staging capacity in bucket_sort

typedef unsigned short u16;
typedef unsigned int u32;
typedef __attribute__((ext_vector_type(8))) short short8;   // 8 bf16 (4 VGPRs)
typedef __attribute__((ext_vector_type(4))) float f32x4;
typedef __attribute__((ext_vector_type(4))) unsigned short ushort4v;

__device__ __forceinline__ float b2f(u16 u) {
    return __uint_as_float(((unsigned)u) << 16);
}
__device__ __forceinline__ u16 f2b(float f) {
    unsigned u = __float_as_uint(f);
    return (u16)((u + 0x7FFF + ((u >> 16) & 1)) >> 16);   // RNE
}

// ---------------------------------------------------------------------------
// K1: blocks 0..23 pack W0/W1/W2(padded) into MFMA B-fragment order;
//     block 24 inits the 196 global bucket cursors to b*CAPB.
// ---------------------------------------------------------------------------
__global__ __launch_bounds__(256) void prep_init(
    const float* __restrict__ W0, const float* __restrict__ W1,
    const float* __restrict__ W2, u16* __restrict__ Wf,
    int* __restrict__ gCur)
{
    const int g = blockIdx.x, t = threadIdx.x;
    if (g == 24) {
        if (t < BKT) gCur[t] = t * CAPB;
        return;
    }
    int u = g * 4 + (t >> 6);               // 0..95
    int set = u >> 5, nt2 = (u >> 2) & 7, kt = u & 3;
    int lane = t & 63;
    const float* W = (set == 0) ? W0 : (set == 1) ? W1 : W2;
    int ld = (set == 2) ? 40 : 128;
    int ncols = (set == 2) ? 40 : 128;
    int n = nt2 * 16 + (lane & 15);
    int kb = kt * 32 + (lane >> 4) * 8;
    u16* dw = Wf + set * 16384 + (size_t)((nt2 * 4 + kt) * 64 + lane) * 8;
#pragma unroll
    for (int j = 0; j < 8; j++) {
        float v = (n < ncols) ? W[(kb + j) * ld + n] : 0.f;
        dw[j] = f2b(v);
    }
}

// ---------------------------------------------------------------------------
// K2: blocks [0,GB): 2-pass scatter with atomic batch reservation.
//       pass 1: LDS histogram of this block's edges over 196 buckets;
//       reserve: cur[b] = atomicAdd(&gCur[b], cnt[b]);
//       pass 2: scatter packed (src<<8 | dstLow) via LDS cursors.
//     blocks [GB,..): layer-0 GEMM  t = bf16(x) @ W0.
// ---------------------------------------------------------------------------
__global__ __launch_bounds__(256) void scatter_gemm0(
    const int* __restrict__ src, const int* __restrict__ dst,
    int* __restrict__ gCur, u32* __restrict__ pairs,
    const float* __restrict__ A, const u16* __restrict__ Wf,
    u16* __restrict__ out, int N, int E)
{
    __shared__ int cnt[BKT];
    __shared__ int cur[BKT];
    const int t = threadIdx.x;
    if (blockIdx.x < GB) {
        const int g = blockIdx.x;
        for (int b = t; b < BKT; b += 256) cnt[b] = 0;
        __syncthreads();
        const int beg = g * EPB, end = min(E, beg + EPB);
        for (int e = beg + t; e < end; e += 256)
            atomicAdd(&cnt[dst[e] >> 8], 1);
        __syncthreads();
        for (int b = t; b < BKT; b += 256)
            cur[b] = atomicAdd(&gCur[b], cnt[b]);
        __syncthreads();
        for (int e = beg + t; e < end; e += 256) {
            int d = dst[e];
            int pos = atomicAdd(&cur[d >> 8], 1);
            pairs[pos] = ((u32)src[e] << 8) | (u32)(d & 255);
        }
        return;
    }
    // ---- gemm0 ----
    const int bx = blockIdx.x - GB;
    const int wave = t >> 6;
    const int lane = t & 63;
    const int m = lane & 15;
    const int q = lane >> 4;
    const int rowBase = bx * 64 + wave * 16;
    const int arow = rowBase + m;
    const bool rowOk = (arow < N);

    short8 af[4];
#pragma unroll
    for (int kt = 0; kt < 4; kt++) {
        if (rowOk) {
            float4 lo = *(const float4*)(A + (size_t)arow * 128 + kt * 32 + q * 8);
            float4 hi = *(const float4*)(A + (size_t)arow * 128 + kt * 32 + q * 8 + 4);
            short8 v;
            v[0] = (short)f2b(lo.x); v[1] = (short)f2b(lo.y);
            v[2] = (short)f2b(lo.z); v[3] = (short)f2b(lo.w);
            v[4] = (short)f2b(hi.x); v[5] = (short)f2b(hi.y);
            v[6] = (short)f2b(hi.z); v[7] = (short)f2b(hi.w);
            af[kt] = v;
        } else {
            af[kt] = (short8)0;
        }
    }

    f32x4 acc[8];
#pragma unroll
    for (int nt = 0; nt < 8; nt++) acc[nt] = (f32x4)0.f;

#pragma unroll
    for (int kt = 0; kt < 4; kt++) {
#pragma unroll
        for (int nt = 0; nt < 8; nt++) {
            short8 bf = *(const short8*)(Wf + (size_t)((nt * 4 + kt) * 64 + lane) * 8);
            acc[nt] = __builtin_amdgcn_mfma_f32_16x16x32_bf16(af[kt], bf, acc[nt], 0, 0, 0);
        }
    }

#pragma unroll
    for (int nt = 0; nt < 8; nt++) {
#pragma unroll
        for (int r = 0; r < 4; r++) {
            int orow = rowBase + q * 4 + r;
            if (orow < N) out[(size_t)orow * 128 + nt * 16 + m] = f2b(acc[nt][r]);
        }
    }
}

// ---------------------------------------------------------------------------
// K3: per-bucket node sort. Every block LDS-scans the 196 final counts to get
// CSR bucket bases (no global scan pass), then sorts its bucket via LDS
// staging. Emits off[] and csr[] (plain src) with coalesced writes.
// ---------------------------------------------------------------------------
__global__ __launch_bounds__(256) void bucket_sort(
    const u32* __restrict__ pairs, const int* __restrict__ gCur,
    int* __restrict__ off, int* __restrict__ csr, int N, int E)
{
    __shared__ int sdeg[256];
    __shared__ int sex[256];
    __shared__ int scur[256];
    __shared__ int stage[CAP];
    const int b = blockIdx.x, t = threadIdx.x;

    // counts -> exclusive prefix (all 196 in LDS, every block redundantly)
    int c0 = (t < BKT) ? (gCur[t] - t * CAPB) : 0;
    sex[t] = c0;
    __syncthreads();
    for (int d = 1; d < 256; d <<= 1) {
        int u = (t >= d) ? sex[t - d] : 0;
        __syncthreads();
        sex[t] += u;
        __syncthreads();
    }
    __shared__ int sBase, sCnt;
    if (t == b) { sBase = sex[t] - c0; sCnt = c0; }
    __syncthreads();
    const int base = sBase;
    const int cnt = sCnt;
    const int pbase = b * CAPB;
    __syncthreads();

    sdeg[t] = 0;
    __syncthreads();
    for (int i = t; i < cnt; i += 256)
        atomicAdd(&sdeg[pairs[pbase + i] & 255], 1);
    __syncthreads();

    int v = sdeg[t];
    sex[t] = v;
    __syncthreads();
    for (int d = 1; d < 256; d <<= 1) {
        int u = (t >= d) ? sex[t - d] : 0;
        __syncthreads();
        sex[t] += u;
        __syncthreads();
    }
    const int excl = sex[t] - v;
    const int node = b * 256 + t;
    if (node < N) off[node] = base + excl;
    if (b == BKT - 1 && t == 0) off[N] = E;
    scur[t] = excl;
    __syncthreads();

    if (cnt <= CAP) {
        for (int i = t; i < cnt; i += 256) {
            u32 p = pairs[pbase + i];
            int pos = atomicAdd(&scur[p & 255], 1);
            stage[pos] = (int)(p >> 8);
        }
        __syncthreads();
        for (int i = t; i < cnt; i += 256) csr[base + i] = stage[i];
    } else {
        for (int i = t; i < cnt; i += 256) {
            u32 p = pairs[pbase + i];
            int pos = atomicAdd(&scur[p & 255], 1);
            csr[base + pos] = (int)(p >> 8);
        }
    }
}

// ---------------------------------------------------------------------------
// K4/K5: FUSED layer: out = ( relu(agg(val) + bias) ) @ W
// block = 64 dst nodes, 512 threads (8 waves).
// phase 1: gather-aggregate 64 rows -> LDS (bf16, row stride 136)
// phase 2: MFMA from LDS; wave = (rowGroup 0..3) x (colHalf 0..1)
// OCOLS clamps stores to the true output width (NT*16 may exceed OSTRIDE:
// the zero-padded W columns must NOT be written -- stride-40 clobber bug, R11).
// NOTE: val and out MUST differ (cross-block gather; in-place is a race).
// ---------------------------------------------------------------------------
template<int NT, int OSTRIDE, int OCOLS>
__global__ __launch_bounds__(512) void agg_gemm_t(
    const u16* __restrict__ val, const int* __restrict__ off,
    const int* __restrict__ csr, const float* __restrict__ bias,
    const u16* __restrict__ Wf, u16* __restrict__ out, int N)
{
    __shared__ u16 A[64][136];   // 17.4 KB
    const int tid = threadIdx.x;
    const int rowBase = blockIdx.x * 64;

    // ---- phase 1: aggregate, bias+relu, bf16 -> LDS
    {
        const int c = tid & 15;          // 16B chunk (8 bf16)
        const int nl = tid >> 4;         // 0..31
        float4 bA = *(const float4*)(bias + c * 8);
        float4 bB = *(const float4*)(bias + c * 8 + 4);
        float bb[8] = {bA.x, bA.y, bA.z, bA.w, bB.x, bB.y, bB.z, bB.w};
#pragma unroll
        for (int g = 0; g < 2; g++) {
            const int lrow = g * 32 + nl;
            const int node = rowBase + lrow;
            float a0[8] = {0, 0, 0, 0, 0, 0, 0, 0};
            float a1[8] = {0, 0, 0, 0, 0, 0, 0, 0};
            if (node < N) {
                const int beg = off[node], end = off[node + 1];
                int i = beg;
                for (; i + 3 < end; i += 4) {
                    int s0 = csr[i];
                    int s1 = csr[i + 1];
                    int s2 = csr[i + 2];
                    int s3 = csr[i + 3];
                    short8 v0 = *(const short8*)(val + (size_t)s0 * 128 + c * 8);
                    short8 v1 = *(const short8*)(val + (size_t)s1 * 128 + c * 8);
                    short8 v2 = *(const short8*)(val + (size_t)s2 * 128 + c * 8);
                    short8 v3 = *(const short8*)(val + (size_t)s3 * 128 + c * 8);
#pragma unroll
                    for (int j = 0; j < 8; j++) {
                        a0[j] += b2f((u16)v0[j]) + b2f((u16)v2[j]);
                        a1[j] += b2f((u16)v1[j]) + b2f((u16)v3[j]);
                    }
                }
                for (; i < end; i++) {
                    int s0 = csr[i];
                    short8 v0 = *(const short8*)(val + (size_t)s0 * 128 + c * 8);
#pragma unroll
                    for (int j = 0; j < 8; j++) a0[j] += b2f((u16)v0[j]);
                }
            }
            short8 o;
#pragma unroll
            for (int j = 0; j < 8; j++)
                o[j] = (short)f2b(fmaxf(a0[j] + a1[j] + bb[j], 0.f));
            *(short8*)&A[lrow][c * 8] = o;
        }
    }
    __syncthreads();

    // ---- phase 2: MFMA from LDS
    const int wave = tid >> 6;           // 0..7
    const int lane = tid & 63;
    const int m = lane & 15;
    const int q = lane >> 4;
    const int rg = wave & 3;             // row group (16 rows)
    const int ch = wave >> 2;            // col half
    const int lrow = rg * 16 + m;

    short8 af[4];
#pragma unroll
    for (int kt = 0; kt < 4; kt++)
        af[kt] = *(const short8*)&A[lrow][kt * 32 + q * 8];

    constexpr int NTH = (NT + 1) / 2;
    const int ntB = ch ? NTH : 0;
    const int ntE = ch ? NT : NTH;

    f32x4 acc[NTH];
#pragma unroll
    for (int i = 0; i < NTH; i++) acc[i] = (f32x4)0.f;

#pragma unroll
    for (int kt = 0; kt < 4; kt++) {
        for (int nt = ntB; nt < ntE; nt++) {
            short8 bf = *(const short8*)(Wf + (size_t)((nt * 4 + kt) * 64 + lane) * 8);
            acc[nt - ntB] = __builtin_amdgcn_mfma_f32_16x16x32_bf16(af[kt], bf, acc[nt - ntB], 0, 0, 0);
        }
    }

    for (int nt = ntB; nt < ntE; nt++) {
        const int col = nt * 16 + m;
        if (col < OCOLS) {
#pragma unroll
            for (int r = 0; r < 4; r++) {
                int orow = rowBase + rg * 16 + q * 4 + r;
                if (orow < N) out[(size_t)orow * OSTRIDE + col] = f2b(acc[nt - ntB][r]);
            }
        }
    }
}

// ---------------------------------------------------------------------------
// K6: aggregate first 40 feats of bf16 stride-40 rows, + b2 -> fp32 d_out
// stride 40 -> 4.0 MB working set ~= per-XCD L2
// ---------------------------------------------------------------------------
__global__ __launch_bounds__(256) void agg40b(
    const u16* __restrict__ val, const int* __restrict__ off,
    const int* __restrict__ csr, const float* __restrict__ b2,
    float* __restrict__ out, int N)
{
    const int c = threadIdx.x & 15;
    const int node = blockIdx.x * 16 + (threadIdx.x >> 4);
    if (node >= N || c >= 10) return;
    const int beg = off[node], end = off[node + 1];

    float a0[4] = {0, 0, 0, 0};
    float a1[4] = {0, 0, 0, 0};
    int i = beg;
    for (; i + 1 < end; i += 2) {
        int s0 = csr[i];
        int s1 = csr[i + 1];
        ushort4v v0 = *(const ushort4v*)(val + (size_t)s0 * 40 + c * 4);
        ushort4v v1 = *(const ushort4v*)(val + (size_t)s1 * 40 + c * 4);
        a0[0] += b2f(v0.x); a0[1] += b2f(v0.y); a0[2] += b2f(v0.z); a0[3] += b2f(v0.w);
        a1[0] += b2f(v1.x); a1[1] += b2f(v1.y); a1[2] += b2f(v1.z); a1[3] += b2f(v1.w);
    }
    if (i < end) {
        int s0 = csr[i];
        ushort4v v0 = *(const ushort4v*)(val + (size_t)s0 * 40 + c * 4);
        a0[0] += b2f(v0.x); a0[1] += b2f(v0.y); a0[2] += b2f(v0.z); a0[3] += b2f(v0.w);
    }
    float4 b = *(const float4*)(b2 + c * 4);
    float4 r;
    r.x = a0[0] + a1[0] + b.x;
    r.y = a0[1] + a1[1] + b.y;
    r.z = a0[2] + a1[2] + b.z;
    r.w = a0[3] + a1[3] + b.w;
    *(float4*)(out + (size_t)node * 40 + c * 4) = r;
}

extern "C" void kernel_launch(void* const* d_in, const int* in_sizes, int n_in,
                              void* d_out, int out_size, void* d_ws, size_t ws_size,
                              hipStream_t stream)
{
    const float* x  = (const float*)d_in[0];
    const int*   ei = (const int*)d_in[1];
    const float* W0 = (const float*)d_in[2];
    const float* b0 = (const float*)d_in[3];
    const float* W1 = (const float*)d_in[4];
    const float* b1 = (const float*)d_in[5];
    const float* W2 = (const float*)d_in[6];
    const float* b2 = (const float*)d_in[7];
    float* out = (float*)d_out;

    const int N = NN, E = EE;
    const int* src = ei;        // edge_index[0]
    const int* dst = ei + E;    // edge_index[1]

    char* ws = (char*)d_ws;
    u16* t     = (u16*)ws;                          // 12.8 MB (layer-0 GEMM out)
    u16* tB    = (u16*)(ws + 12800000);             // 12.8 MB (layer-1 fused out)
    u16* t2    = (u16*)(ws + 25600000);             // 4.0 MB (layer-2, stride 40)
    u16* Wf    = (u16*)(ws + 29600000);             // 96 KB (frag-packed W)
    int* off   = (int*)(ws + 29700000);             // 200 KB (N+1)
    int* csr   = (int*)(ws + 29900008);             // 3.2 MB
    int* gCur  = (int*)(ws + 33100008);             // 784 B (bucket cursors)
    u32* pairs = (u32*)(ws + 33100800);             // 4.82 MB (196*6144*4)

    const int tileGrid = (N + 63) / 64;             // 782
    const int agg40Grid = (N + 15) / 16;            // 3125

    // K1: weight packing + bucket-cursor init
    prep_init<<<25, 256, 0, stream>>>(W0, W1, W2, Wf, gCur);
    // K2: batch-reserved scatter + layer-0 GEMM (independent, one launch)
    scatter_gemm0<<<GB + tileGrid, 256, 0, stream>>>(src, dst, gCur, pairs,
                                                     x, Wf, t, N, E);
    // K3: per-bucket sort -> off[] + csr[]
    bucket_sort<<<BKT, 256, 0, stream>>>(pairs, gCur, off, csr, N, E);

    // K4: layer 1 fused: tB = relu(agg(t) + b0) @ W1
    agg_gemm_t<8, 128, 128><<<tileGrid, 512, 0, stream>>>(t, off, csr, b0,
                                                          Wf + 16384, tB, N);
    // K5: layer 2 fused: t2 = relu(agg(tB) + b1) @ W2pad, 40 true cols
    agg_gemm_t<3, 40, 40><<<tileGrid, 512, 0, stream>>>(tB, off, csr, b1,
                                                        Wf + 32768, t2, N);
    // K6: out = agg40(t2) + b2
    agg40b<<<agg40Grid, 256, 0, stream>>>(t2, off, csr, b2, out, N);
}